// Round 10
// baseline (214.487 us; speedup 1.0000x reference)
//
#include <hip/hip_runtime.h>
#include <math.h>

// Problem constants
#define BATCH 8192
#define NFEAT 256
#define NH1   100     // fc1 width (K of fc2)
#define NH2   50      // fc2 width (N of fc2)

typedef __attribute__((ext_vector_type(8))) _Float16 half8;   // MFMA A/B frag
typedef __attribute__((ext_vector_type(2))) _Float16 h2v;     // packed fp16 pair
typedef __attribute__((ext_vector_type(2))) __fp16   fp16x2;  // cvt_pkrtz result
typedef __attribute__((ext_vector_type(4))) float    float4v; // MFMA acc

__device__ __forceinline__ h2v pkrtz(float a, float b) {
    fp16x2 r = __builtin_amdgcn_cvt_pkrtz(a, b);
    return __builtin_bit_cast(h2v, r);
}

// ---- single fused main kernel: no prep, no transpose, no LDS, no ticket.
// One wave = (64 batch rows, ALL 64 N-cols, one feature): minimal total
// fc1+epilogue VALU (no duplication). All weight conversion in-register
// (fp32 loads + cvt_pkrtz). K=100 exact: kk=0..2 full 32-steps, kk=3 masked
// (k=96..99 live in qd==0 lanes only, rest exact zeros). o in [50,64):
// clamped addresses (in-bounds), neutralized by w3=0 in the epilogue.
__global__ __launch_bounds__(256, 3) void nam_mfma(
    const float* __restrict__ x,
    const float* __restrict__ W1, const float* __restrict__ b1,
    const float* __restrict__ W2, const float* __restrict__ b2,
    const float* __restrict__ W3,
    float* __restrict__ out)
{
    const int t  = threadIdx.x;
    const int wv = t >> 6;
    const int ln = t & 15;
    const int qd = (t >> 4) & 3;
    const int f  = blockIdx.y * 4 + wv;
    const int b0 = blockIdx.x * 64;

    const float* __restrict__ w1g = W1 + f * NH1;
    const float* __restrict__ b1g = b1 + f * NH1;
    const float* __restrict__ w2g = W2 + (size_t)f * NH2 * NH1;

    // x gather (16 lines per load, L2-served; x hits HBM once at line grain)
    h2v xh[4];
#pragma unroll
    for (int mt = 0; mt < 4; ++mt) {
        const float xs = x[(size_t)(b0 + mt * 16 + ln) * NFEAT + f];
        xh[mt] = pkrtz(xs, xs);
    }

    float4v acc[4][4];
#pragma unroll
    for (int mt = 0; mt < 4; ++mt)
#pragma unroll
        for (int nt = 0; nt < 4; ++nt) acc[mt][nt] = (float4v){0.f, 0.f, 0.f, 0.f};

    // o-clamp per n-tile (addresses in-bounds; garbage rows killed by w3=0)
    int osrc[4];
#pragma unroll
    for (int nt = 0; nt < 4; ++nt) {
        const int o = nt * 16 + ln;
        osrc[nt] = (o < NH2) ? o : 0;
    }

    // ---- kk = 0..2 : full 32-wide K steps ----
#pragma unroll
    for (int kk = 0; kk < 3; ++kk) {
        const int kb = kk * 32 + qd * 8;            // <= 88, +7 in-bounds

        const float4 wA = *(const float4*)(w1g + kb);
        const float4 wB = *(const float4*)(w1g + kb + 4);
        const float4 cA = *(const float4*)(b1g + kb);
        const float4 cB = *(const float4*)(b1g + kb + 4);
        const h2v wh0 = pkrtz(wA.x, wA.y), wh1 = pkrtz(wA.z, wA.w);
        const h2v wh2 = pkrtz(wB.x, wB.y), wh3 = pkrtz(wB.z, wB.w);
        const h2v ch0 = pkrtz(cA.x, cA.y), ch1 = pkrtz(cA.z, cA.w);
        const h2v ch2 = pkrtz(cB.x, cB.y), ch3 = pkrtz(cB.z, cB.w);

        half8 bf[4];
#pragma unroll
        for (int nt = 0; nt < 4; ++nt) {
            const float* p = w2g + osrc[nt] * NH1 + kb;   // 16B-aligned
            const float4 u0 = *(const float4*)(p);
            const float4 u1 = *(const float4*)(p + 4);
            h2v* bp = (h2v*)&bf[nt];
            bp[0] = pkrtz(u0.x, u0.y); bp[1] = pkrtz(u0.z, u0.w);
            bp[2] = pkrtz(u1.x, u1.y); bp[3] = pkrtz(u1.z, u1.w);
        }

        const h2v z2 = (h2v){(_Float16)0.f, (_Float16)0.f};
#pragma unroll
        for (int mt = 0; mt < 4; ++mt) {
            half8 af;
            h2v* ap = (h2v*)&af;
            ap[0] = __builtin_elementwise_max(wh0 * xh[mt] + ch0, z2);
            ap[1] = __builtin_elementwise_max(wh1 * xh[mt] + ch1, z2);
            ap[2] = __builtin_elementwise_max(wh2 * xh[mt] + ch2, z2);
            ap[3] = __builtin_elementwise_max(wh3 * xh[mt] + ch3, z2);
#pragma unroll
            for (int nt = 0; nt < 4; ++nt)
                acc[mt][nt] = __builtin_amdgcn_mfma_f32_16x16x32_f16(
                    af, bf[nt], acc[mt][nt], 0, 0, 0);
        }
    }

    // ---- kk = 3 : k = 96..99 live (qd==0 lanes), 100..127 exact zero ----
    {
        const bool live = (qd == 0);
        const float4 z4 = make_float4(0.f, 0.f, 0.f, 0.f);
        const float4 wA = *(const float4*)(w1g + 96);   // uniform, in-bounds
        const float4 cA = *(const float4*)(b1g + 96);
        const float4 wz = live ? wA : z4;
        const float4 cz = live ? cA : z4;
        const h2v wh0 = pkrtz(wz.x, wz.y), wh1 = pkrtz(wz.z, wz.w);
        const h2v ch0 = pkrtz(cz.x, cz.y), ch1 = pkrtz(cz.z, cz.w);

        const h2v z2 = (h2v){(_Float16)0.f, (_Float16)0.f};

        half8 bf[4];
#pragma unroll
        for (int nt = 0; nt < 4; ++nt) {
            const float4 u = *(const float4*)(w2g + osrc[nt] * NH1 + 96);
            const float4 uz = live ? u : z4;
            h2v* bp = (h2v*)&bf[nt];
            bp[0] = pkrtz(uz.x, uz.y); bp[1] = pkrtz(uz.z, uz.w);
            bp[2] = z2;                bp[3] = z2;
        }
#pragma unroll
        for (int mt = 0; mt < 4; ++mt) {
            half8 af;
            h2v* ap = (h2v*)&af;
            ap[0] = __builtin_elementwise_max(wh0 * xh[mt] + ch0, z2);  // relu(0)=0 for qd>0
            ap[1] = __builtin_elementwise_max(wh1 * xh[mt] + ch1, z2);
            ap[2] = z2;
            ap[3] = z2;
#pragma unroll
            for (int nt = 0; nt < 4; ++nt)
                acc[mt][nt] = __builtin_amdgcn_mfma_f32_16x16x32_f16(
                    af, bf[nt], acc[mt][nt], 0, 0, 0);
        }
    }

    // ---- epilogue: h2 = relu(acc + b2); contrib = h2 . w3; reduce over o ----
    const float* __restrict__ b2g = b2 + f * NH2;
    const float* __restrict__ w3g = W3 + f * NH2;

    float rp[4][4] = {{0.f}, {0.f}, {0.f}, {0.f}};
#pragma unroll
    for (int nt = 0; nt < 4; ++nt) {
        const int o = nt * 16 + ln;
        const float bo = b2g[osrc[nt]];
        const float wo = (o < NH2) ? w3g[osrc[nt]] : 0.f;   // kills clamped cols
#pragma unroll
        for (int mt = 0; mt < 4; ++mt)
#pragma unroll
            for (int r = 0; r < 4; ++r)
                rp[mt][r] = fmaf(fmaxf(acc[mt][nt][r] + bo, 0.f), wo, rp[mt][r]);
    }
#pragma unroll
    for (int mt = 0; mt < 4; ++mt)
#pragma unroll
        for (int r = 0; r < 4; ++r) {
            float v = rp[mt][r];
            v += __shfl_xor(v, 1);
            v += __shfl_xor(v, 2);
            v += __shfl_xor(v, 4);
            v += __shfl_xor(v, 8);
            if (ln == 0)
                atomicAdd(out + b0 + mt * 16 + qd * 4 + r, v);  // C row = qd*4+r
        }
}

__global__ __launch_bounds__(256) void nam_finish(
    float* __restrict__ out, const float* __restrict__ bias)
{
    const int b = blockIdx.x * blockDim.x + threadIdx.x;
    out[b] = 1.0f / (1.0f + expf(-(out[b] + bias[0])));
}

extern "C" void kernel_launch(void* const* d_in, const int* in_sizes, int n_in,
                              void* d_out, int out_size, void* d_ws, size_t ws_size,
                              hipStream_t stream) {
    const float* x    = (const float*)d_in[0];
    const float* W1   = (const float*)d_in[1];
    const float* b1   = (const float*)d_in[2];
    const float* W2   = (const float*)d_in[3];
    const float* b2   = (const float*)d_in[4];
    const float* W3   = (const float*)d_in[5];
    const float* bias = (const float*)d_in[6];
    float* out = (float*)d_out;

    // out accumulated via atomics -> zero first (harness poisons 0xAA)
    (void)hipMemsetAsync(out, 0, (size_t)BATCH * sizeof(float), stream);

    nam_mfma<<<dim3(BATCH / 64, NFEAT / 4), 256, 0, stream>>>(
        x, W1, b1, W2, b2, W3, out);

    nam_finish<<<BATCH / 256, 256, 0, stream>>>(out, bias);
}

// Round 11
// 150.654 us; speedup vs baseline: 1.4237x; 1.4237x over previous
//
#include <hip/hip_runtime.h>
#include <math.h>

// Problem constants
#define BATCH 8192
#define NFEAT 256
#define NH1   100     // fc1 width (K of fc2)
#define NH2   50      // fc2 width (N of fc2)
#define KP    128     // K padded: 4 MFMA k-steps of 32
#define FPB   8       // features per block (inner loop, LDS double-buffered)
#define RPB   256     // batch rows per block (64 per wave)

typedef __attribute__((ext_vector_type(8))) _Float16 half8;   // MFMA A/B frag
typedef __attribute__((ext_vector_type(2))) _Float16 h2v;     // packed fp16 pair
typedef __attribute__((ext_vector_type(2))) __fp16   fp16x2;  // cvt_pkrtz result
typedef __attribute__((ext_vector_type(4))) float    float4v; // MFMA acc

__device__ __forceinline__ h2v pkrtz(float a, float b) {
    fp16x2 r = __builtin_amdgcn_cvt_pkrtz(a, b);
    return __builtin_bit_cast(h2v, r);
}

// ---- workspace layout (fp32 units from ws start) ----
// w2h : NFEAT*8192 f16 = 4 MB (fragment-ordered, zero-padded)
// w1h/b1h : NFEAT*KP f16 (zero-padded)
#define OFF_W1H  (NFEAT * 8192 / 2)
#define OFF_B1H  (OFF_W1H + NFEAT * KP / 2)

// ---- prep: one block per feature. Weight conversion ONLY (coalesced,
// done once — R10 showed in-main conversion is a disaster). Also zeroes
// this feature's slice of out (replaces the memset node).
__global__ __launch_bounds__(256) void prep(
    const float* __restrict__ W1, const float* __restrict__ b1,
    const float* __restrict__ W2, float* __restrict__ ws,
    float* __restrict__ out)
{
    const int f = blockIdx.x;
    const int t = threadIdx.x;
    _Float16* w1h = (_Float16*)(ws + OFF_W1H) + f * KP;
    _Float16* b1h = (_Float16*)(ws + OFF_B1H) + f * KP;
    _Float16* w2h = (_Float16*)ws + (size_t)f * 8192;

    if (t < KP) {
        w1h[t] = (_Float16)((t < NH1) ? W1[f * NH1 + t] : 0.f);
        b1h[t] = (_Float16)((t < NH1) ? b1[f * NH1 + t] : 0.f);
    }
    if (t < 32) out[f * 32 + t] = 0.f;

    // w2h[f][kk][nt][lane][j] = f16(W2[f][o=16*nt+(lane&15)][h=32*kk+8*(lane>>4)+j])
    const float* w2g = W2 + (size_t)f * NH2 * NH1;
#pragma unroll
    for (int i = 0; i < 32; ++i) {
        const int e    = i * 256 + t;        // 0..8191
        const int j    = e & 7;
        const int lane = (e >> 3) & 63;
        const int nt   = (e >> 9) & 3;
        const int kk   = e >> 11;
        const int o    = nt * 16 + (lane & 15);
        const int h    = kk * 32 + (lane >> 4) * 8 + j;
        w2h[e] = (_Float16)((o < NH2 && h < NH1) ? w2g[o * NH1 + h] : 0.f);
    }
}

// ---- main: block = 4 waves x 256 rows, all on ONE feature at a time,
// looping over FPB features. B-fragments staged once per (block,f) into
// LDS (double-buffered via registers, 1 barrier/f) -> 4x less L2 traffic,
// LDS-latency B reads. Per-row contributions accumulate in registers across
// the 8 features -> atomics /8. x read directly: one 64B line per row
// covers all 8 features (L1-hot) -> no transpose pass needed.
__global__ __launch_bounds__(256, 3) void nam_mfma(
    const float* __restrict__ x,
    const float* __restrict__ ws,
    const float* __restrict__ b2,
    const float* __restrict__ W3,
    float* __restrict__ out)
{
    __shared__ _Float16 lds[2][8192];      // 2 x 16 KB fragment buffers

    const int t   = threadIdx.x;
    const int wv  = t >> 6;
    const int l64 = t & 63;
    const int ln  = t & 15;
    const int qd  = (t >> 4) & 3;
    const int rowbase = blockIdx.x * RPB + wv * 64;
    const int f0      = blockIdx.y * FPB;

    const _Float16* w2h = (const _Float16*)ws;
    const _Float16* w1h = (const _Float16*)(ws + OFF_W1H);
    const _Float16* b1h = (const _Float16*)(ws + OFF_B1H);

    int osrc[4];
#pragma unroll
    for (int nt = 0; nt < 4; ++nt) {
        const int o = nt * 16 + ln;
        osrc[nt] = (o < NH2) ? o : 0;      // clamped; killed by wo=0
    }

    // stage f0 into buffer 0 (coalesced int4 copy: 64B/thread)
    {
        const int4* src = (const int4*)(w2h + (size_t)f0 * 8192);
        int4* dst = (int4*)lds[0];
#pragma unroll
        for (int i = 0; i < 4; ++i) dst[i * 256 + t] = src[i * 256 + t];
    }
    __syncthreads();

    float rp[4][4] = {{0.f}, {0.f}, {0.f}, {0.f}};   // contrib, summed over f

#pragma unroll 1
    for (int fi = 0; fi < FPB; ++fi) {
        const int f = f0 + fi;
        const _Float16* B = lds[fi & 1];

        // prefetch next feature's fragments into registers (latency hidden
        // by this feature's MFMA work); LDS store after compute, 1 barrier.
        int4 nxt[4];
        if (fi + 1 < FPB) {
            const int4* src = (const int4*)(w2h + (size_t)(f + 1) * 8192);
#pragma unroll
            for (int i = 0; i < 4; ++i) nxt[i] = src[i * 256 + t];
        }

        // x for this feature (same 64B line across all fi -> L1-hot)
        h2v xh[4];
#pragma unroll
        for (int mt = 0; mt < 4; ++mt) {
            const float xs = x[(size_t)(rowbase + mt * 16 + ln) * NFEAT + f];
            xh[mt] = pkrtz(xs, xs);
        }

        float4v acc[4][4];
#pragma unroll
        for (int mt = 0; mt < 4; ++mt)
#pragma unroll
            for (int nt = 0; nt < 4; ++nt) acc[mt][nt] = (float4v){0.f, 0.f, 0.f, 0.f};

        const h2v* wp = (const h2v*)(w1h + f * KP);
        const h2v* cp = (const h2v*)(b1h + f * KP);
        const h2v z2 = (h2v){(_Float16)0.f, (_Float16)0.f};

#pragma unroll
        for (int kk = 0; kk < 4; ++kk) {
            half8 bf[4];
#pragma unroll
            for (int nt = 0; nt < 4; ++nt)
                bf[nt] = *(const half8*)(B + (kk * 4 + nt) * 512 + l64 * 8);

            const int pb = kk * 16 + qd * 4;       // h2v pair index
            const h2v w0 = wp[pb], w1 = wp[pb + 1], w2 = wp[pb + 2], w3 = wp[pb + 3];
            const h2v c0 = cp[pb], c1 = cp[pb + 1], c2 = cp[pb + 2], c3 = cp[pb + 3];

#pragma unroll
            for (int mt = 0; mt < 4; ++mt) {
                half8 af;
                h2v* ap = (h2v*)&af;
                ap[0] = __builtin_elementwise_max(w0 * xh[mt] + c0, z2);
                ap[1] = __builtin_elementwise_max(w1 * xh[mt] + c1, z2);
                ap[2] = __builtin_elementwise_max(w2 * xh[mt] + c2, z2);
                ap[3] = __builtin_elementwise_max(w3 * xh[mt] + c3, z2);
#pragma unroll
                for (int nt = 0; nt < 4; ++nt)
                    acc[mt][nt] = __builtin_amdgcn_mfma_f32_16x16x32_f16(
                        af, bf[nt], acc[mt][nt], 0, 0, 0);
            }
        }

        // epilogue for this f: h2 = relu(acc + b2); rp += h2 * w3
        const float* __restrict__ b2g = b2 + f * NH2;
        const float* __restrict__ w3g = W3 + f * NH2;
#pragma unroll
        for (int nt = 0; nt < 4; ++nt) {
            const int o = nt * 16 + ln;
            const float bo = b2g[osrc[nt]];
            const float wo = (o < NH2) ? w3g[osrc[nt]] : 0.f;
#pragma unroll
            for (int mt = 0; mt < 4; ++mt)
#pragma unroll
                for (int r = 0; r < 4; ++r)
                    rp[mt][r] = fmaf(fmaxf(acc[mt][nt][r] + bo, 0.f), wo, rp[mt][r]);
        }

        // write prefetched fragments into the other buffer; single barrier
        // per f (prior barrier guarantees nobody still reads that buffer).
        if (fi + 1 < FPB) {
            int4* dst = (int4*)lds[(fi + 1) & 1];
#pragma unroll
            for (int i = 0; i < 4; ++i) dst[i * 256 + t] = nxt[i];
        }
        __syncthreads();
    }

    // ---- final: shuffle-reduce rp over the 16 columns, one atomic per row
#pragma unroll
    for (int mt = 0; mt < 4; ++mt)
#pragma unroll
        for (int r = 0; r < 4; ++r) {
            float v = rp[mt][r];
            v += __shfl_xor(v, 1);
            v += __shfl_xor(v, 2);
            v += __shfl_xor(v, 4);
            v += __shfl_xor(v, 8);
            if (ln == 0)
                atomicAdd(out + rowbase + mt * 16 + qd * 4 + r, v);
        }
}

__global__ __launch_bounds__(256) void nam_finish(
    float* __restrict__ out, const float* __restrict__ bias)
{
    const int b = blockIdx.x * blockDim.x + threadIdx.x;
    out[b] = 1.0f / (1.0f + expf(-(out[b] + bias[0])));
}

extern "C" void kernel_launch(void* const* d_in, const int* in_sizes, int n_in,
                              void* d_out, int out_size, void* d_ws, size_t ws_size,
                              hipStream_t stream) {
    const float* x    = (const float*)d_in[0];
    const float* W1   = (const float*)d_in[1];
    const float* b1   = (const float*)d_in[2];
    const float* W2   = (const float*)d_in[3];
    const float* b2   = (const float*)d_in[4];
    const float* W3   = (const float*)d_in[5];
    const float* bias = (const float*)d_in[6];
    float* out = (float*)d_out;
    float* ws  = (float*)d_ws;   // ~4.3 MB used

    prep<<<NFEAT, 256, 0, stream>>>(W1, b1, W2, ws, out);

    nam_mfma<<<dim3(BATCH / RPB, NFEAT / FPB), 256, 0, stream>>>(
        x, ws, b2, W3, out);

    nam_finish<<<BATCH / 256, 256, 0, stream>>>(out, bias);
}